// Round 8
// baseline (160.488 us; speedup 1.0000x reference)
//
#include <hip/hip_runtime.h>
#include <hip/hip_bf16.h>
#include <cstdint>

#define IDIM 1024
#define HID  256

typedef __attribute__((ext_vector_type(4))) float f32x4;
typedef __attribute__((ext_vector_type(8))) short short8;
typedef __attribute__((ext_vector_type(4))) unsigned int u32x4;

__device__ __forceinline__ unsigned pk_bf16(float a, float b) {
  __hip_bfloat162 h = __float22bfloat162_rn(make_float2(a, b));
  unsigned r; __builtin_memcpy(&r, &h, 4); return r;
}

__device__ __forceinline__ void gl2lds16(const void* src, void* dst) {
  __builtin_amdgcn_global_load_lds(
      reinterpret_cast<const __attribute__((address_space(1))) unsigned int*>(
          reinterpret_cast<uintptr_t>(src)),
      reinterpret_cast<__attribute__((address_space(3))) unsigned int*>(
          reinterpret_cast<uintptr_t>(dst)),
      16, 0, 0);
}

#define SYNC1() do {                       \
  __builtin_amdgcn_sched_barrier(0);       \
  __builtin_amdgcn_s_barrier();            \
  __builtin_amdgcn_sched_barrier(0); } while (0)

#define SYNC2(N) do {                                  \
  __builtin_amdgcn_sched_barrier(0);                   \
  asm volatile("s_waitcnt vmcnt(" #N ")");             \
  __builtin_amdgcn_sched_barrier(0);                   \
  __builtin_amdgcn_s_barrier();                        \
  __builtin_amdgcn_sched_barrier(0); } while (0)

// ---------------------------------------------------------------------------
// Prep: w1t = per-K-step tiled, transposed, ln_w-scaled bf16 W1.
//   elem (n, k) -> w1t[ (k>>5)*8192 + n*32 + (k&31) ]
//   t2[n] = sum_k ln_w[k]*W1[k][n]; tc1[n] = sum_k ln_b[k]*W1[k][n] + b1[n]
// ---------------------------------------------------------------------------
__global__ __launch_bounds__(256)
void prep_kernel(const float* __restrict__ W1, const float* __restrict__ lnw,
                 const float* __restrict__ lnb, const float* __restrict__ b1,
                 unsigned short* __restrict__ w1t, float* __restrict__ t2g,
                 float* __restrict__ tc1g) {
  const int t  = threadIdx.x;
  const int ni = t & 3, kg = t >> 2;     // kg: 16-wide k-group 0..63
  const int n  = blockIdx.x * 4 + ni;
  const int k0 = kg * 16;
  float s1 = 0.f, s2 = 0.f;
  unsigned pk[8];
#pragma unroll
  for (int j = 0; j < 16; j += 2) {
    const int k = k0 + j;
    const float v0 = W1[(size_t)k * HID + n];
    const float v1 = W1[(size_t)(k + 1) * HID + n];
    const float sc0 = lnw[k] * v0, sc1 = lnw[k + 1] * v1;
    s2 += sc0 + sc1;
    s1 = fmaf(lnb[k], v0, fmaf(lnb[k + 1], v1, s1));
    pk[j >> 1] = pk_bf16(sc0, sc1);
  }
  const int sT = kg >> 1, kk0 = (kg & 1) * 16;
  u32x4* dst = reinterpret_cast<u32x4*>(w1t + (size_t)sT * 8192 + n * 32 + kk0);
  dst[0] = u32x4{pk[0], pk[1], pk[2], pk[3]};
  dst[1] = u32x4{pk[4], pk[5], pk[6], pk[7]};
  __shared__ float red[2][64][4];
  red[0][kg][ni] = s1; red[1][kg][ni] = s2;
  __syncthreads();
  if (t < 4) {
    float a = 0.f, b = 0.f;
    for (int i = 0; i < 64; ++i) { a += red[0][i][t]; b += red[1][i][t]; }
    const int nn = blockIdx.x * 4 + t;
    tc1g[nn] = a + b1[nn];
    t2g[nn]  = b;
  }
}

// ---------------------------------------------------------------------------
// Head. Block = 64 rows x 256 cols, 4 waves: wave w -> band=w>>1 (32 rows),
// slab=w&1 (128 cols). BK=32, 32 K-steps.
// A: NO LDS. Lane loads its MFMA fragments direct from global (2 rows x 32B,
//    fully coalesced 128B/row per wave), 2-deep named reg pipeline; stats
//    accumulate in-register from the fp32 values before bf16 pack.
// B: w1t step tiles (16KiB) -> LDS dbuf via global_load_lds, swizzled
//    chunk^=(row>>1)&3 (conflict-free for the 64B-row ds_read_b128 pattern).
// Sync/step: SYNC1 (barrier, WAR) ... issue B(s+2),A(s+2) ... SYNC2 vmcnt(12)
//    = A(s+1)4+B(s+2)4+A(s+2)4 outstanding -> B(s+1) landed, ~1.7-step
//    latency budget for both streams; vmcnt never drained until the tail.
// ---------------------------------------------------------------------------
__global__ __launch_bounds__(256, 3)
void head_kernel(const float* __restrict__ emb,
                 const unsigned short* __restrict__ w1t,
                 const float* __restrict__ t2g, const float* __restrict__ tc1g,
                 const float* __restrict__ w2g, const float* __restrict__ b2g,
                 float* __restrict__ out) {
  __shared__ __align__(16) char smB[2][16384];  // [buf][row*64B], swizzled
  __shared__ float statsS[64][2];               // [block row][mu*rs, rs]
  __shared__ float poutS[2][2][32][2];          // [band][slab][row][o]

  const int t    = threadIdx.x;
  const int l    = t & 63;
  const int w    = t >> 6;
  const int lr   = l & 15;
  const int lk   = l >> 4;
  const int band = w >> 1;
  const int slab = w & 1;
  const int m0   = blockIdx.x * 64;

  // A: direct per-lane fragment sources (rows band*32 + {lr, 16+lr})
  const float* const aP0 = emb + (size_t)(m0 + band * 32 + lr) * IDIM + lk * 8;
  const float* const aP1 = emb + (size_t)(m0 + band * 32 + 16 + lr) * IDIM + lk * 8;

  // B staging: pre-swizzled global source (G21); dst is linear wave slab
  const unsigned short* const bSrc =
      w1t + ((size_t)w * 16 + (l >> 2)) * 32 + ((l & 3) ^ ((l >> 3) & 3)) * 8;

  // B fragment read base (swizzled chunk)
  const int bRdOff = (slab * 128 + lr) * 64 + ((lk ^ ((lr >> 1) & 3)) * 16);

  f32x4 acc[2][8];
#pragma unroll
  for (int i = 0; i < 2; ++i)
#pragma unroll
    for (int j = 0; j < 8; ++j) acc[i][j] = f32x4{0.f, 0.f, 0.f, 0.f};
  float sum0 = 0.f, ssq0 = 0.f, sum1 = 0.f, ssq1 = 0.f;

  f32x4 A00, A01, A02, A03;  // set 0 (even steps)
  f32x4 A10, A11, A12, A13;  // set 1 (odd steps)

#define ISSUE_A(s, R0, R1, R2, R3) do {                                   \
    const f32x4* _p0 = reinterpret_cast<const f32x4*>(aP0 + (size_t)(s) * 32); \
    R0 = _p0[0]; R1 = _p0[1];                                             \
    const f32x4* _p1 = reinterpret_cast<const f32x4*>(aP1 + (size_t)(s) * 32); \
    R2 = _p1[0]; R3 = _p1[1]; } while (0)

#define ISSUE_B(s, buf) do {                                              \
    const unsigned short* _s0 = bSrc + (size_t)(s) * 8192;                \
    char* _d = smB[(buf)] + w * 1024;                                     \
    gl2lds16(_s0,        _d);                                             \
    gl2lds16(_s0 + 2048, _d + 4096);                                      \
    gl2lds16(_s0 + 4096, _d + 8192);                                      \
    gl2lds16(_s0 + 6144, _d + 12288); } while (0)

#define STATS8(X, Y, SU, SQ) do {                                         \
    SU += ((X[0] + X[1]) + (X[2] + X[3])) + ((Y[0] + Y[1]) + (Y[2] + Y[3])); \
    float _q = SQ;                                                        \
    _q = fmaf(X[0], X[0], _q); _q = fmaf(X[1], X[1], _q);                 \
    _q = fmaf(X[2], X[2], _q); _q = fmaf(X[3], X[3], _q);                 \
    _q = fmaf(Y[0], Y[0], _q); _q = fmaf(Y[1], Y[1], _q);                 \
    _q = fmaf(Y[2], Y[2], _q); _q = fmaf(Y[3], Y[3], _q);                 \
    SQ = _q; } while (0)

#define COMPUTE(buf, R0, R1, R2, R3) do {                                 \
    STATS8(R0, R1, sum0, ssq0);                                           \
    STATS8(R2, R3, sum1, ssq1);                                           \
    const u32x4 _u0 = {pk_bf16(R0[0], R0[1]), pk_bf16(R0[2], R0[3]),      \
                       pk_bf16(R1[0], R1[1]), pk_bf16(R1[2], R1[3])};     \
    const u32x4 _u1 = {pk_bf16(R2[0], R2[1]), pk_bf16(R2[2], R2[3]),      \
                       pk_bf16(R3[0], R3[1]), pk_bf16(R3[2], R3[3])};     \
    short8 _av0, _av1;                                                    \
    __builtin_memcpy(&_av0, &_u0, 16);                                    \
    __builtin_memcpy(&_av1, &_u1, 16);                                    \
    const char* _Bb = smB[(buf)] + bRdOff;                                \
    short8 _bv;                                                           \
    _bv = *reinterpret_cast<const short8*>(_Bb);                          \
    acc[0][0] = __builtin_amdgcn_mfma_f32_16x16x32_bf16(_av0, _bv, acc[0][0], 0, 0, 0); \
    acc[1][0] = __builtin_amdgcn_mfma_f32_16x16x32_bf16(_av1, _bv, acc[1][0], 0, 0, 0); \
    _bv = *reinterpret_cast<const short8*>(_Bb + 1024);                   \
    acc[0][1] = __builtin_amdgcn_mfma_f32_16x16x32_bf16(_av0, _bv, acc[0][1], 0, 0, 0); \
    acc[1][1] = __builtin_amdgcn_mfma_f32_16x16x32_bf16(_av1, _bv, acc[1][1], 0, 0, 0); \
    _bv = *reinterpret_cast<const short8*>(_Bb + 2048);                   \
    acc[0][2] = __builtin_amdgcn_mfma_f32_16x16x32_bf16(_av0, _bv, acc[0][2], 0, 0, 0); \
    acc[1][2] = __builtin_amdgcn_mfma_f32_16x16x32_bf16(_av1, _bv, acc[1][2], 0, 0, 0); \
    _bv = *reinterpret_cast<const short8*>(_Bb + 3072);                   \
    acc[0][3] = __builtin_amdgcn_mfma_f32_16x16x32_bf16(_av0, _bv, acc[0][3], 0, 0, 0); \
    acc[1][3] = __builtin_amdgcn_mfma_f32_16x16x32_bf16(_av1, _bv, acc[1][3], 0, 0, 0); \
    _bv = *reinterpret_cast<const short8*>(_Bb + 4096);                   \
    acc[0][4] = __builtin_amdgcn_mfma_f32_16x16x32_bf16(_av0, _bv, acc[0][4], 0, 0, 0); \
    acc[1][4] = __builtin_amdgcn_mfma_f32_16x16x32_bf16(_av1, _bv, acc[1][4], 0, 0, 0); \
    _bv = *reinterpret_cast<const short8*>(_Bb + 5120);                   \
    acc[0][5] = __builtin_amdgcn_mfma_f32_16x16x32_bf16(_av0, _bv, acc[0][5], 0, 0, 0); \
    acc[1][5] = __builtin_amdgcn_mfma_f32_16x16x32_bf16(_av1, _bv, acc[1][5], 0, 0, 0); \
    _bv = *reinterpret_cast<const short8*>(_Bb + 6144);                   \
    acc[0][6] = __builtin_amdgcn_mfma_f32_16x16x32_bf16(_av0, _bv, acc[0][6], 0, 0, 0); \
    acc[1][6] = __builtin_amdgcn_mfma_f32_16x16x32_bf16(_av1, _bv, acc[1][6], 0, 0, 0); \
    _bv = *reinterpret_cast<const short8*>(_Bb + 7168);                   \
    acc[0][7] = __builtin_amdgcn_mfma_f32_16x16x32_bf16(_av0, _bv, acc[0][7], 0, 0, 0); \
    acc[1][7] = __builtin_amdgcn_mfma_f32_16x16x32_bf16(_av1, _bv, acc[1][7], 0, 0, 0); \
  } while (0)

#define STEP(s, buf, R0, R1, R2, R3) do {                                 \
    COMPUTE(buf, R0, R1, R2, R3);                                         \
    SYNC1();                                                              \
    ISSUE_B((s) + 2, buf);                                                \
    ISSUE_A((s) + 2, R0, R1, R2, R3);                                     \
    SYNC2(12); } while (0)

  // prologue: B(0), A(0), B(1), A(1); wait B(0) landed (12 younger in flight)
  ISSUE_B(0, 0);
  ISSUE_A(0, A00, A01, A02, A03);
  ISSUE_B(1, 1);
  ISSUE_A(1, A10, A11, A12, A13);
  SYNC2(12);

#pragma unroll 1
  for (int s0 = 0; s0 < 30; s0 += 2) {
    STEP(s0,     0, A00, A01, A02, A03);
    STEP(s0 + 1, 1, A10, A11, A12, A13);
  }
  // tail: steps 30, 31 — no more staging
  COMPUTE(0, A00, A01, A02, A03);
  SYNC2(4);   // only A(31) may remain outstanding; B(31) landed
  COMPUTE(1, A10, A11, A12, A13);

  // row stats: reduce each lane's k-quarter over lk (xor 16, 32)
  sum0 += __shfl_xor(sum0, 16); sum0 += __shfl_xor(sum0, 32);
  ssq0 += __shfl_xor(ssq0, 16); ssq0 += __shfl_xor(ssq0, 32);
  sum1 += __shfl_xor(sum1, 16); sum1 += __shfl_xor(sum1, 32);
  ssq1 += __shfl_xor(ssq1, 16); ssq1 += __shfl_xor(ssq1, 32);
  if (slab == 0 && lk == 0) {
    const float mu0  = sum0 * (1.f / 1024.f);
    const float var0 = ssq0 * (1.f / 1024.f) - mu0 * mu0;
    const float rs0  = rsqrtf(var0 + 1e-5f);
    statsS[band * 32 + lr][0] = mu0 * rs0;
    statsS[band * 32 + lr][1] = rs0;
    const float mu1  = sum1 * (1.f / 1024.f);
    const float var1 = ssq1 * (1.f / 1024.f) - mu1 * mu1;
    const float rs1  = rsqrtf(var1 + 1e-5f);
    statsS[band * 32 + 16 + lr][0] = mu1 * rs1;
    statsS[band * 32 + 16 + lr][1] = rs1;
  }
  __syncthreads();

  // epilogue: folded-LN affine -> exact GELU -> second GEMM (256 -> 2)
  float po0[2][4], po1[2][4];
#pragma unroll
  for (int mi = 0; mi < 2; ++mi)
#pragma unroll
    for (int j = 0; j < 4; ++j) { po0[mi][j] = 0.f; po1[mi][j] = 0.f; }
#pragma unroll
  for (int ni = 0; ni < 8; ++ni) {
    const int n = slab * 128 + ni * 16 + lr;
    const float t2n = t2g[n];
    const float tcn = tc1g[n];
    const float w20 = w2g[n * 2];
    const float w21 = w2g[n * 2 + 1];
#pragma unroll
    for (int mi = 0; mi < 2; ++mi) {
#pragma unroll
      for (int j = 0; j < 4; ++j) {
        const int rl = mi * 16 + lk * 4 + j;
        const float mrs = statsS[band * 32 + rl][0];
        const float rs  = statsS[band * 32 + rl][1];
        const float z  = fmaf(rs, acc[mi][ni][j], fmaf(-mrs, t2n, tcn));
        const float hh = 0.5f * z * (1.f + erff(z * 0.70710678118654752f));
        po0[mi][j] = fmaf(hh, w20, po0[mi][j]);
        po1[mi][j] = fmaf(hh, w21, po1[mi][j]);
      }
    }
  }
#pragma unroll
  for (int mi = 0; mi < 2; ++mi)
#pragma unroll
    for (int j = 0; j < 4; ++j) {
#pragma unroll
      for (int d = 1; d < 16; d <<= 1) {
        po0[mi][j] += __shfl_xor(po0[mi][j], d);
        po1[mi][j] += __shfl_xor(po1[mi][j], d);
      }
    }
  if (lr == 0) {
#pragma unroll
    for (int mi = 0; mi < 2; ++mi)
#pragma unroll
      for (int j = 0; j < 4; ++j) {
        const int rl = mi * 16 + lk * 4 + j;
        poutS[band][slab][rl][0] = po0[mi][j];
        poutS[band][slab][rl][1] = po1[mi][j];
      }
  }
  __syncthreads();
  if (t < 128) {
    const int r = t >> 1, o = t & 1;
    const float v = poutS[r >> 5][0][r & 31][o] + poutS[r >> 5][1][r & 31][o];
    out[(size_t)(m0 + r) * 2 + o] = v + b2g[o];
  }
}

extern "C" void kernel_launch(void* const* d_in, const int* in_sizes, int n_in,
                              void* d_out, int out_size, void* d_ws, size_t ws_size,
                              hipStream_t stream) {
  const float* emb = (const float*)d_in[0];
  const float* lnw = (const float*)d_in[1];
  const float* lnb = (const float*)d_in[2];
  const float* W1  = (const float*)d_in[3];
  const float* b1  = (const float*)d_in[4];
  const float* W2  = (const float*)d_in[5];
  const float* b2  = (const float*)d_in[6];
  float* out = (float*)d_out;

  unsigned short* w1t = (unsigned short*)d_ws;   // 512 KiB (step-tiled)
  float* t2g  = (float*)((char*)d_ws + 524288);
  float* tc1g = (float*)((char*)d_ws + 524288 + 1024);

  prep_kernel<<<HID / 4, 256, 0, stream>>>(W1, lnw, lnb, b1, w1t, t2g, tc1g);
  head_kernel<<<65536 / 64, 256, 0, stream>>>(emb, w1t, t2g, tc1g, W2, b2, out);
}

// Round 9
// 116.682 us; speedup vs baseline: 1.3754x; 1.3754x over previous
//
#include <hip/hip_runtime.h>
#include <hip/hip_bf16.h>
#include <cstdint>

#define IDIM 1024
#define HID  256

typedef __attribute__((ext_vector_type(4))) float f32x4;
typedef __attribute__((ext_vector_type(8))) short short8;
typedef __attribute__((ext_vector_type(4))) unsigned int u32x4;

__device__ __forceinline__ unsigned pk_bf16(float a, float b) {
  __hip_bfloat162 h = __float22bfloat162_rn(make_float2(a, b));
  unsigned r; __builtin_memcpy(&r, &h, 4); return r;
}

__device__ __forceinline__ void gl2lds16(const void* src, void* dst) {
  __builtin_amdgcn_global_load_lds(
      reinterpret_cast<const __attribute__((address_space(1))) unsigned int*>(
          reinterpret_cast<uintptr_t>(src)),
      reinterpret_cast<__attribute__((address_space(3))) unsigned int*>(
          reinterpret_cast<uintptr_t>(dst)),
      16, 0, 0);
}

// WAR barrier: ds-reads drained, then barrier. vmcnt NOT touched.
#define SYNC1() do {                                   \
  __builtin_amdgcn_sched_barrier(0);                   \
  asm volatile("s_waitcnt lgkmcnt(0)");                \
  __builtin_amdgcn_sched_barrier(0);                   \
  __builtin_amdgcn_s_barrier();                        \
  __builtin_amdgcn_sched_barrier(0); } while (0)

// counted vmcnt + publish barrier
#define SYNC2(N) do {                                  \
  __builtin_amdgcn_sched_barrier(0);                   \
  asm volatile("s_waitcnt vmcnt(" #N ")");             \
  __builtin_amdgcn_sched_barrier(0);                   \
  __builtin_amdgcn_s_barrier();                        \
  __builtin_amdgcn_sched_barrier(0); } while (0)

// ---------------------------------------------------------------------------
// Prep: w1t = per-64k-step tiled, transposed, ln_w-scaled bf16 W1.
//   elem (n, k) -> w1t[(k>>6)*16384 + n*64 + (k&63)]   (tile = 256n x 64k)
//   t2[n] = sum_k ln_w[k]*W1[k][n]; tc1[n] = sum_k ln_b[k]*W1[k][n] + b1[n]
// ---------------------------------------------------------------------------
__global__ __launch_bounds__(256)
void prep_kernel(const float* __restrict__ W1, const float* __restrict__ lnw,
                 const float* __restrict__ lnb, const float* __restrict__ b1,
                 unsigned short* __restrict__ w1t, float* __restrict__ t2g,
                 float* __restrict__ tc1g) {
  const int t  = threadIdx.x;
  const int ni = t & 3, kg = t >> 2;     // kg: 16-wide k-group 0..63
  const int n  = blockIdx.x * 4 + ni;
  const int k0 = kg * 16;
  float s1 = 0.f, s2 = 0.f;
  unsigned pk[8];
#pragma unroll
  for (int j = 0; j < 16; j += 2) {
    const int k = k0 + j;
    const float v0 = W1[(size_t)k * HID + n];
    const float v1 = W1[(size_t)(k + 1) * HID + n];
    const float sc0 = lnw[k] * v0, sc1 = lnw[k + 1] * v1;
    s2 += sc0 + sc1;
    s1 = fmaf(lnb[k], v0, fmaf(lnb[k + 1], v1, s1));
    pk[j >> 1] = pk_bf16(sc0, sc1);
  }
  const int tile = kg >> 2, kq = (kg & 3) * 16;
  u32x4* dst = reinterpret_cast<u32x4*>(w1t + (size_t)tile * 16384 + n * 64 + kq);
  dst[0] = u32x4{pk[0], pk[1], pk[2], pk[3]};
  dst[1] = u32x4{pk[4], pk[5], pk[6], pk[7]};
  __shared__ float red[2][64][4];
  red[0][kg][ni] = s1; red[1][kg][ni] = s2;
  __syncthreads();
  if (t < 4) {
    float a = 0.f, b = 0.f;
    for (int i = 0; i < 64; ++i) { a += red[0][i][t]; b += red[1][i][t]; }
    const int nn = blockIdx.x * 4 + t;
    tc1g[nn] = a + b1[nn];
    t2g[nn]  = b;
  }
}

// ---------------------------------------------------------------------------
// Head. Block = 64 rows x 256 cols, 4 waves: wave w -> band=w>>1 (32 rows),
// slab=w&1 (128 cols). BK=64, 16 K-steps.
// A: no LDS — lane loads MFMA fragments direct (2 rows x 2 kk x 32B), 2-deep
//    named reg sets; stats in-register.  B: 32-KiB step tiles -> LDS dbuf via
//    gl2lds, chunk^=(row&7) swizzle (verified conflict-free in R8).
// Per step: COMPUTE | SYNC1(lgkm+bar) | ISSUE_B(s+2) ISSUE_A(s+2) | SYNC2(16).
// vmcnt(16) = next step's 8 B + 8 A ops stay in flight; never drains to 0
// until the tail. launch_bounds(256,2): 256-VGPR budget -> NO SPILL (the R8
// killer: (256,3) forced VGPR=84 + 47 MB scratch round-trip).
// ---------------------------------------------------------------------------
__global__ __launch_bounds__(256, 2)
void head_kernel(const float* __restrict__ emb,
                 const unsigned short* __restrict__ w1t,
                 const float* __restrict__ t2g, const float* __restrict__ tc1g,
                 const float* __restrict__ w2g, const float* __restrict__ b2g,
                 float* __restrict__ out) {
  __shared__ __align__(16) char smB[2][32768];  // [buf][n*128B], swizzled
  __shared__ float statsS[64][2];               // [block row][mu*rs, rs]
  __shared__ float poutS[2][2][32][2];          // [band][slab][row][o]

  const int t    = threadIdx.x;
  const int l    = t & 63;
  const int w    = t >> 6;
  const int lr   = l & 15;
  const int lk   = l >> 4;
  const int band = w >> 1;
  const int slab = w & 1;
  const int m0   = blockIdx.x * 64;

  // A: per-lane fragment sources (rows band*32 + {lr, 16+lr}), k-base lk*8
  const float* const aP0 = emb + (size_t)(m0 + band * 32 + lr) * IDIM + lk * 8;
  const float* const aP1 = emb + (size_t)(m0 + band * 32 + 16 + lr) * IDIM + lk * 8;

  // B staging: pre-swizzled global source (elements); dst linear, lane*16B
  const unsigned short* const bSrc =
      w1t + ((size_t)w * 64 + (l >> 3)) * 64 + ((l & 7) ^ ((l >> 3) & 7)) * 8;

  // B fragment read byte offsets (kk=0 / kk=1), swizzled chunk
  const int bRd0 = (slab * 128 + lr) * 128 + ((lk ^ (lr & 7)) * 16);
  const int bRd1 = bRd0 ^ 64;

  f32x4 acc[2][8];
#pragma unroll
  for (int i = 0; i < 2; ++i)
#pragma unroll
    for (int j = 0; j < 8; ++j) acc[i][j] = f32x4{0.f, 0.f, 0.f, 0.f};
  float sum0 = 0.f, ssq0 = 0.f, sum1 = 0.f, ssq1 = 0.f;

  // A pipeline: 2 named sets x 8 f32x4 (row0 kk0:X0X1 kk1:X2X3; row1 Y...)
  f32x4 P0, P1, P2, P3, P4, P5, P6, P7;  // set 0 (even steps)
  f32x4 Q0, Q1, Q2, Q3, Q4, Q5, Q6, Q7;  // set 1 (odd steps)

#define ISSUE_A(s, R0, R1, R2, R3, R4, R5, R6, R7) do {                    \
    const f32x4* _q0 = reinterpret_cast<const f32x4*>(aP0 + (size_t)(s) * 64); \
    R0 = _q0[0]; R1 = _q0[1]; R2 = _q0[8]; R3 = _q0[9];                    \
    const f32x4* _q1 = reinterpret_cast<const f32x4*>(aP1 + (size_t)(s) * 64); \
    R4 = _q1[0]; R5 = _q1[1]; R6 = _q1[8]; R7 = _q1[9]; } while (0)

#define ISSUE_B(s, buf) do {                                               \
    const unsigned short* _s0 = bSrc + (size_t)(s) * 16384;                \
    char* _d = smB[(buf)] + w * 8192;                                      \
    gl2lds16(_s0,        _d);                                              \
    gl2lds16(_s0 +  512, _d + 1024);                                       \
    gl2lds16(_s0 + 1024, _d + 2048);                                       \
    gl2lds16(_s0 + 1536, _d + 3072);                                       \
    gl2lds16(_s0 + 2048, _d + 4096);                                       \
    gl2lds16(_s0 + 2560, _d + 5120);                                       \
    gl2lds16(_s0 + 3072, _d + 6144);                                       \
    gl2lds16(_s0 + 3584, _d + 7168); } while (0)

#define STATS4(Xa, Xb, SU, SQ) do {                                        \
    SU += ((Xa[0] + Xa[1]) + (Xa[2] + Xa[3])) +                            \
          ((Xb[0] + Xb[1]) + (Xb[2] + Xb[3]));                             \
    float _q = SQ;                                                         \
    _q = fmaf(Xa[0], Xa[0], _q); _q = fmaf(Xa[1], Xa[1], _q);              \
    _q = fmaf(Xa[2], Xa[2], _q); _q = fmaf(Xa[3], Xa[3], _q);              \
    _q = fmaf(Xb[0], Xb[0], _q); _q = fmaf(Xb[1], Xb[1], _q);              \
    _q = fmaf(Xb[2], Xb[2], _q); _q = fmaf(Xb[3], Xb[3], _q);              \
    SQ = _q; } while (0)

#define PACK(Xa, Xb, AV) do {                                              \
    const u32x4 _u = {pk_bf16(Xa[0], Xa[1]), pk_bf16(Xa[2], Xa[3]),        \
                      pk_bf16(Xb[0], Xb[1]), pk_bf16(Xb[2], Xb[3])};       \
    __builtin_memcpy(&AV, &_u, 16); } while (0)

#define MMA8(AV0, AV1, off, K)  /* one kk half: 8 ds_read + 16 MFMA */     \
  do {                                                                     \
    short8 _bv;                                                            \
    _bv = *reinterpret_cast<const short8*>(_Bb + (off));                   \
    acc[0][0] = __builtin_amdgcn_mfma_f32_16x16x32_bf16(AV0, _bv, acc[0][0], 0, 0, 0); \
    acc[1][0] = __builtin_amdgcn_mfma_f32_16x16x32_bf16(AV1, _bv, acc[1][0], 0, 0, 0); \
    _bv = *reinterpret_cast<const short8*>(_Bb + (off) + 2048);            \
    acc[0][1] = __builtin_amdgcn_mfma_f32_16x16x32_bf16(AV0, _bv, acc[0][1], 0, 0, 0); \
    acc[1][1] = __builtin_amdgcn_mfma_f32_16x16x32_bf16(AV1, _bv, acc[1][1], 0, 0, 0); \
    _bv = *reinterpret_cast<const short8*>(_Bb + (off) + 4096);            \
    acc[0][2] = __builtin_amdgcn_mfma_f32_16x16x32_bf16(AV0, _bv, acc[0][2], 0, 0, 0); \
    acc[1][2] = __builtin_amdgcn_mfma_f32_16x16x32_bf16(AV1, _bv, acc[1][2], 0, 0, 0); \
    _bv = *reinterpret_cast<const short8*>(_Bb + (off) + 6144);            \
    acc[0][3] = __builtin_amdgcn_mfma_f32_16x16x32_bf16(AV0, _bv, acc[0][3], 0, 0, 0); \
    acc[1][3] = __builtin_amdgcn_mfma_f32_16x16x32_bf16(AV1, _bv, acc[1][3], 0, 0, 0); \
    _bv = *reinterpret_cast<const short8*>(_Bb + (off) + 8192);            \
    acc[0][4] = __builtin_amdgcn_mfma_f32_16x16x32_bf16(AV0, _bv, acc[0][4], 0, 0, 0); \
    acc[1][4] = __builtin_amdgcn_mfma_f32_16x16x32_bf16(AV1, _bv, acc[1][4], 0, 0, 0); \
    _bv = *reinterpret_cast<const short8*>(_Bb + (off) + 10240);           \
    acc[0][5] = __builtin_amdgcn_mfma_f32_16x16x32_bf16(AV0, _bv, acc[0][5], 0, 0, 0); \
    acc[1][5] = __builtin_amdgcn_mfma_f32_16x16x32_bf16(AV1, _bv, acc[1][5], 0, 0, 0); \
    _bv = *reinterpret_cast<const short8*>(_Bb + (off) + 12288);           \
    acc[0][6] = __builtin_amdgcn_mfma_f32_16x16x32_bf16(AV0, _bv, acc[0][6], 0, 0, 0); \
    acc[1][6] = __builtin_amdgcn_mfma_f32_16x16x32_bf16(AV1, _bv, acc[1][6], 0, 0, 0); \
    _bv = *reinterpret_cast<const short8*>(_Bb + (off) + 14336);           \
    acc[0][7] = __builtin_amdgcn_mfma_f32_16x16x32_bf16(AV0, _bv, acc[0][7], 0, 0, 0); \
    acc[1][7] = __builtin_amdgcn_mfma_f32_16x16x32_bf16(AV1, _bv, acc[1][7], 0, 0, 0); \
  } while (0)

#define COMPUTE(buf, R0, R1, R2, R3, R4, R5, R6, R7) do {                  \
    STATS4(R0, R1, sum0, ssq0); STATS4(R2, R3, sum0, ssq0);                \
    STATS4(R4, R5, sum1, ssq1); STATS4(R6, R7, sum1, ssq1);                \
    short8 _a00, _a01, _a10, _a11;                                         \
    PACK(R0, R1, _a00); PACK(R4, R5, _a10);   /* kk=0 */                   \
    PACK(R2, R3, _a01); PACK(R6, R7, _a11);   /* kk=1 */                   \
    const char* _Bb = smB[(buf)];                                          \
    MMA8(_a00, _a10, bRd0, 0);                                             \
    MMA8(_a01, _a11, bRd1, 1);                                             \
  } while (0)

#define STEP(s, buf, R0, R1, R2, R3, R4, R5, R6, R7) do {                  \
    COMPUTE(buf, R0, R1, R2, R3, R4, R5, R6, R7);                          \
    SYNC1();                                                               \
    ISSUE_B((s) + 2, buf);                                                 \
    ISSUE_A((s) + 2, R0, R1, R2, R3, R4, R5, R6, R7);                      \
    SYNC2(16); } while (0)

  // prologue: B(0),A(0),B(1),A(1); vmcnt(16) -> B(0),A(0) landed
  ISSUE_B(0, 0);
  ISSUE_A(0, P0, P1, P2, P3, P4, P5, P6, P7);
  ISSUE_B(1, 1);
  ISSUE_A(1, Q0, Q1, Q2, Q3, Q4, Q5, Q6, Q7);
  SYNC2(16);

#pragma unroll 1
  for (int s = 0; s < 14; s += 2) {
    STEP(s,     0, P0, P1, P2, P3, P4, P5, P6, P7);
    STEP(s + 1, 1, Q0, Q1, Q2, Q3, Q4, Q5, Q6, Q7);
  }
  // tail: steps 14, 15 (B(15),A(15) already in flight)
  COMPUTE(0, P0, P1, P2, P3, P4, P5, P6, P7);
  SYNC2(0);
  COMPUTE(1, Q0, Q1, Q2, Q3, Q4, Q5, Q6, Q7);

  // row stats: reduce over the 4 lk lanes holding the same row
  sum0 += __shfl_xor(sum0, 16); sum0 += __shfl_xor(sum0, 32);
  ssq0 += __shfl_xor(ssq0, 16); ssq0 += __shfl_xor(ssq0, 32);
  sum1 += __shfl_xor(sum1, 16); sum1 += __shfl_xor(sum1, 32);
  ssq1 += __shfl_xor(ssq1, 16); ssq1 += __shfl_xor(ssq1, 32);
  if (slab == 0 && lk == 0) {
    const float mu0  = sum0 * (1.f / 1024.f);
    const float var0 = ssq0 * (1.f / 1024.f) - mu0 * mu0;
    const float rs0  = rsqrtf(var0 + 1e-5f);
    statsS[band * 32 + lr][0] = mu0 * rs0;
    statsS[band * 32 + lr][1] = rs0;
    const float mu1  = sum1 * (1.f / 1024.f);
    const float var1 = ssq1 * (1.f / 1024.f) - mu1 * mu1;
    const float rs1  = rsqrtf(var1 + 1e-5f);
    statsS[band * 32 + 16 + lr][0] = mu1 * rs1;
    statsS[band * 32 + 16 + lr][1] = rs1;
  }
  __syncthreads();

  // epilogue: folded-LN affine -> exact GELU -> second GEMM (256 -> 2)
  float po0[2][4], po1[2][4];
#pragma unroll
  for (int mi = 0; mi < 2; ++mi)
#pragma unroll
    for (int j = 0; j < 4; ++j) { po0[mi][j] = 0.f; po1[mi][j] = 0.f; }
#pragma unroll
  for (int ni = 0; ni < 8; ++ni) {
    const int n = slab * 128 + ni * 16 + lr;
    const float t2n = t2g[n];
    const float tcn = tc1g[n];
    const float w20 = w2g[n * 2];
    const float w21 = w2g[n * 2 + 1];
#pragma unroll
    for (int mi = 0; mi < 2; ++mi) {
#pragma unroll
      for (int j = 0; j < 4; ++j) {
        const int rl = mi * 16 + lk * 4 + j;
        const float mrs = statsS[band * 32 + rl][0];
        const float rs  = statsS[band * 32 + rl][1];
        const float z  = fmaf(rs, acc[mi][ni][j], fmaf(-mrs, t2n, tcn));
        const float hh = 0.5f * z * (1.f + erff(z * 0.70710678118654752f));
        po0[mi][j] = fmaf(hh, w20, po0[mi][j]);
        po1[mi][j] = fmaf(hh, w21, po1[mi][j]);
      }
    }
  }
#pragma unroll
  for (int mi = 0; mi < 2; ++mi)
#pragma unroll
    for (int j = 0; j < 4; ++j) {
#pragma unroll
      for (int d = 1; d < 16; d <<= 1) {
        po0[mi][j] += __shfl_xor(po0[mi][j], d);
        po1[mi][j] += __shfl_xor(po1[mi][j], d);
      }
    }
  if (lr == 0) {
#pragma unroll
    for (int mi = 0; mi < 2; ++mi)
#pragma unroll
      for (int j = 0; j < 4; ++j) {
        const int rl = mi * 16 + lk * 4 + j;
        poutS[band][slab][rl][0] = po0[mi][j];
        poutS[band][slab][rl][1] = po1[mi][j];
      }
  }
  __syncthreads();
  if (t < 128) {
    const int r = t >> 1, o = t & 1;
    const float v = poutS[r >> 5][0][r & 31][o] + poutS[r >> 5][1][r & 31][o];
    out[(size_t)(m0 + r) * 2 + o] = v + b2g[o];
  }
}

extern "C" void kernel_launch(void* const* d_in, const int* in_sizes, int n_in,
                              void* d_out, int out_size, void* d_ws, size_t ws_size,
                              hipStream_t stream) {
  const float* emb = (const float*)d_in[0];
  const float* lnw = (const float*)d_in[1];
  const float* lnb = (const float*)d_in[2];
  const float* W1  = (const float*)d_in[3];
  const float* b1  = (const float*)d_in[4];
  const float* W2  = (const float*)d_in[5];
  const float* b2  = (const float*)d_in[6];
  float* out = (float*)d_out;

  unsigned short* w1t = (unsigned short*)d_ws;   // 512 KiB (step-tiled)
  float* t2g  = (float*)((char*)d_ws + 524288);
  float* tc1g = (float*)((char*)d_ws + 524288 + 1024);

  prep_kernel<<<HID / 4, 256, 0, stream>>>(W1, lnw, lnb, b1, w1t, t2g, tc1g);
  head_kernel<<<65536 / 64, 256, 0, stream>>>(emb, w1t, t2g, tc1g, W2, b2, out);
}